// Round 9
// baseline (377.898 us; speedup 1.0000x reference)
//
#include <hip/hip_runtime.h>
#include <hip/hip_bf16.h>

#define O_N 128
#define D_N 128
#define F_LS 64
#define T_MAX 128
#define FE_N 16
#define H_GRU 64
#define NH 128
#define NO 64
#define PH 128
#define NGRP 1024

typedef _Float16 f16;
typedef __fp16 hf2 __attribute__((ext_vector_type(2)));
typedef f16 f16x4 __attribute__((ext_vector_type(4)));
typedef f16 f16x8 __attribute__((ext_vector_type(8)));
typedef float f32x4 __attribute__((ext_vector_type(4)));

__device__ __forceinline__ float fast_sigmoid(float x) {
    return __builtin_amdgcn_rcpf(1.f + __expf(-x));
}

// ---- fused: encoders (blocks 0..255) + counting sort (block 256) ----------
__global__ __launch_bounds__(256) void k_pre(
    const float* __restrict__ O_feats, const float* __restrict__ D_feats,
    const float* __restrict__ WO1, const float* __restrict__ bO1,
    const float* __restrict__ WO2, const float* __restrict__ bO2,
    const float* __restrict__ WO3, const float* __restrict__ bO3,
    const float* __restrict__ WD1, const float* __restrict__ bD1,
    const float* __restrict__ WD2, const float* __restrict__ bD2,
    const float* __restrict__ WD3, const float* __restrict__ bD3,
    const float* __restrict__ Wp1, const float* __restrict__ bp1,
    const int* __restrict__ lengths,
    float* __restrict__ PA, float* __restrict__ PBt,
    int* __restrict__ perm, float* __restrict__ d_out)
{
    const int t = threadIdx.x;
    if (blockIdx.x == 256) {
        __shared__ int cnt[130];
        __shared__ int suf[130];
        if (t < 130) cnt[t] = 0;
        __syncthreads();
        for (int i = t; i < 16384; i += 256) atomicAdd(&cnt[lengths[i]], 1);
        __syncthreads();
        if (t < 130) suf[t] = cnt[t];
        __syncthreads();
        for (int d = 1; d < 130; d <<= 1) {
            int v = 0;
            if (t < 130) { v = suf[t]; if (t + d < 130) v += suf[t + d]; }
            __syncthreads();
            if (t < 130) suf[t] = v;
            __syncthreads();
        }
        if (t < 129) cnt[t] = (t + 1 < 130) ? suf[t + 1] : 0;
        __syncthreads();
        for (int i = t; i < 16384; i += 256) {
            int pos = atomicAdd(&cnt[lengths[i]], 1);
            perm[pos] = i;
        }
        return;
    }

    __shared__ float h1[NH];
    __shared__ float h2[NH];
    __shared__ float ev[NO];
    const int b = blockIdx.x;
    const int enc = b >> 7;
    const int row = b & 127;
    if (b == 0 && t == 0) d_out[0] = 0.f;

    const float* x  = (enc ? D_feats : O_feats) + row * F_LS;
    const float* W1 = enc ? WD1 : WO1;  const float* b1 = enc ? bD1 : bO1;
    const float* W2 = enc ? WD2 : WO2;  const float* b2 = enc ? bD2 : bO2;
    const float* W3 = enc ? WD3 : WO3;  const float* b3 = enc ? bD3 : bO3;

    if (t < 128) {
        float a = b1[t];
        #pragma unroll 8
        for (int k = 0; k < F_LS; ++k) a += x[k] * W1[k * NH + t];
        h1[t] = fmaxf(a, 0.f);
    }
    __syncthreads();

    if (t < 128) {
        float a = b2[t];
        #pragma unroll 8
        for (int k = 0; k < NH; ++k) a += h1[k] * W2[k * NH + t];
        h2[t] = fmaxf(a, 0.f);
    }
    __syncthreads();

    if (t < NO) {
        float a = b3[t];
        #pragma unroll 8
        for (int k = 0; k < NH; ++k) a += h2[k] * W3[k * NO + t];
        ev[t] = a;
    }
    __syncthreads();

    if (t < 128) {
        const float* Wp = Wp1 + (enc ? NO * PH : 0);
        float a = 0.f;
        #pragma unroll 8
        for (int k = 0; k < NO; ++k) a += ev[k] * Wp[k * PH + t];
        if (enc) PBt[t * 128 + row] = a + bp1[t];   // transposed + bias folded
        else     PA[row * PH + t] = a;
    }
}

// ---- GRU: 512 blocks, TWO interleaved group-streams per block -------------
// Block b runs groups {b, 1023-b} (sorted desc => lenA >= lenB, lenA in
// [64,128]). Wall = 128 double-steps regardless of dispatch topology
// (length-optimal schedule: can't beat the longest sequence). Stream B's
// independent MFMA/gate chains issue from the same wave while stream A's
// chain stalls (in-wave ILP replaces the TLP that r8 lost at 2 blocks/CU).
// One barrier per double-step. LDS padded to ~54KB so exactly 2 blocks/CU
// (pigeonhole at grid 512). x staged per stream through LDS double buffers
// in 8-step phases via global_load_lds; xbuf [row][chunk][pair].
// Wave w owns hidden cols [16w,16w+16); lane(q,n): pair n, cols 16w+4q+0..3.
__global__ __launch_bounds__(256, 2) void k_gru(
    const float* __restrict__ seqs, const int* __restrict__ lengths,
    const int* __restrict__ perm,
    const float* __restrict__ W_ih, const float* __restrict__ b_ih,
    const float* __restrict__ W_hh, const float* __restrict__ b_hh,
    const float* __restrict__ Ws, const float* __restrict__ bs,
    const float* __restrict__ PA, const float* __restrict__ PBt,
    const float* __restrict__ Wp2, const float* __restrict__ bp2,
    float* __restrict__ d_out)
{
    __shared__ __align__(16) f16 hbuf[2][2][16 * 72];   // [grp][buf][pair][72]
    __shared__ __align__(16) float4 xbuf[2][2][8][64];  // [grp][buf][row][ch*16+pair]
    __shared__ float red[2][64];
    __shared__ float pad_[2944];                        // force <=2 blocks/CU
    const int tid = threadIdx.x;
    if (tid > 100000) pad_[0] = 1.f;                    // keep pad_ allocated
    const int w  = tid >> 6;
    const int l  = tid & 63;
    const int q  = l >> 4;
    const int n  = l & 15;
    const int c  = w * 16 + n;          // W-frag column (m-row of A-tile)
    const int colbase = w * 16 + q * 4; // this lane's 4 hidden cols
    const int gA = blockIdx.x;
    const int gB = (NGRP - 1) - blockIdx.x;
    const int pbA = gA * 16;
    const int pbB = gB * 16;
    const float S_RZ = -1.4426950408889634f;   // -log2(e)
    const float S_N  =  2.8853900817779268f;   // 2*log2(e)

    // W fragments (A-operand via m=lane&15) -- shared by both streams:
    f16x8 wh[3][2], wi[3];
    #pragma unroll
    for (int gg = 0; gg < 3; ++gg) {
        const int gb = gg * 64;
        const float s = (gg < 2) ? S_RZ : S_N;
        #pragma unroll
        for (int ks = 0; ks < 2; ++ks)
            #pragma unroll
            for (int jj = 0; jj < 8; ++jj)
                wh[gg][ks][jj] = (f16)(W_hh[(ks * 32 + q * 8 + jj) * 192 + gb + c] * s);
        #pragma unroll
        for (int jj = 0; jj < 8; ++jj) {
            int k = q * 8 + jj;
            wi[gg][jj] = (k < FE_N) ? (f16)(W_ih[k * 192 + gb + c] * s) : (f16)0.f;
        }
    }
    f32x4 c_r, c_z, c_hn, c_xn;
    float wsc[4];
    #pragma unroll
    for (int r = 0; r < 4; ++r) {
        int col = colbase + r;
        c_r[r]  = S_RZ * (b_ih[col] + b_hh[col]);
        c_z[r]  = S_RZ * (b_ih[64 + col] + b_hh[64 + col]);
        c_hn[r] = S_N * b_hh[128 + col];
        c_xn[r] = S_N * b_ih[128 + col];
        wsc[r]  = Ws[col];
    }
    const int mypA = perm[pbA + n];
    const int mypB = perm[pbB + n];
    const int mylenA = lengths[mypA];
    const int mylenB = lengths[mypB];
    const int maxlenA = lengths[perm[pbA]];   // sorted desc -> group max
    const int maxlenB = lengths[perm[pbB]];   // <= maxlenA

    // staging sources: lane l covers slot l = (chunk l>>4, pair l&15)
    const float* xsrcA = seqs + (size_t)perm[pbA + (l & 15)] * (T_MAX * FE_N)
                        + (l >> 4) * 4;
    const float* xsrcB = seqs + (size_t)perm[pbB + (l & 15)] * (T_MAX * FE_N)
                        + (l >> 4) * 4;

    // zero h buffer 0 of both streams (2 x 2304 B)
    if (tid < 144) { f16x8 z8 = {}; *(f16x8*)&hbuf[0][0][tid * 8] = z8; }
    if (tid < 144) { f16x8 z8 = {}; *(f16x8*)&hbuf[1][0][tid * 8] = z8; }

    // stage phase 0 for both streams: wave w loads rows {w, w+4}
    #pragma unroll
    for (int rr = 0; rr < 2; ++rr) {
        const int r8 = w + rr * 4;
        __builtin_amdgcn_global_load_lds(
            (const __attribute__((address_space(1))) void*)(xsrcA + (size_t)r8 * FE_N),
            (__attribute__((address_space(3))) void*)&xbuf[0][0][r8][0], 16, 0, 0);
        __builtin_amdgcn_global_load_lds(
            (const __attribute__((address_space(1))) void*)(xsrcB + (size_t)r8 * FE_N),
            (__attribute__((address_space(3))) void*)&xbuf[1][0][r8][0], 16, 0, 0);
    }
    float holdA[4] = {0.f, 0.f, 0.f, 0.f};
    float holdB[4] = {0.f, 0.f, 0.f, 0.f};
    const f16x8 zero8 = {};
    __syncthreads();   // drains phase-0 staging + hbuf zeroing

    #pragma unroll 1
    for (int t = 0; t < maxlenA; ++t) {
        const int cur = t & 1;
        const int xb  = (t >> 3) & 1;
        const int row = t & 7;
        const bool bAlive = (t < maxlenB);          // block-uniform

        // ---- issue all LDS h reads first ----
        f16x8 bhA0 = *(const f16x8*)&hbuf[0][cur][n * 72 + 8 * q];
        f16x8 bhA1 = *(const f16x8*)&hbuf[0][cur][n * 72 + 32 + 8 * q];
        f16x8 bhB0 = zero8, bhB1 = zero8;
        if (bAlive) {
            bhB0 = *(const f16x8*)&hbuf[1][cur][n * 72 + 8 * q];
            bhB1 = *(const f16x8*)&hbuf[1][cur][n * 72 + 32 + 8 * q];
        }

        // ---- stage next 8-step phase (once per 8 steps) ----
        if (row == 0) {
            const int nb = xb ^ 1;
            if (t + 8 < maxlenA) {
                #pragma unroll
                for (int rr = 0; rr < 2; ++rr) {
                    const int rl = w + rr * 4;
                    int rg = t + 8 + rl;
                    rg = rg < T_MAX ? rg : T_MAX - 1;
                    __builtin_amdgcn_global_load_lds(
                        (const __attribute__((address_space(1))) void*)(xsrcA + (size_t)rg * FE_N),
                        (__attribute__((address_space(3))) void*)&xbuf[0][nb][rl][0], 16, 0, 0);
                }
            }
            if (t + 8 < maxlenB) {
                #pragma unroll
                for (int rr = 0; rr < 2; ++rr) {
                    const int rl = w + rr * 4;
                    int rg = t + 8 + rl;
                    rg = rg < T_MAX ? rg : T_MAX - 1;
                    __builtin_amdgcn_global_load_lds(
                        (const __attribute__((address_space(1))) void*)(xsrcB + (size_t)rg * FE_N),
                        (__attribute__((address_space(3))) void*)&xbuf[1][nb][rl][0], 16, 0, 0);
                }
            }
        }

        // ---- x converts ----
        f16x8 axA = zero8, axB = zero8;
        if (q < 2) {
            float4 a0 = xbuf[0][xb][row][32 * q + n];
            float4 a1 = xbuf[0][xb][row][32 * q + 16 + n];
            union { f16x8 v8; hf2 v2[4]; } u;
            u.v2[0] = __builtin_amdgcn_cvt_pkrtz(a0.x, a0.y);
            u.v2[1] = __builtin_amdgcn_cvt_pkrtz(a0.z, a0.w);
            u.v2[2] = __builtin_amdgcn_cvt_pkrtz(a1.x, a1.y);
            u.v2[3] = __builtin_amdgcn_cvt_pkrtz(a1.z, a1.w);
            axA = u.v8;
        }
        if (bAlive && q < 2) {
            float4 b0 = xbuf[1][xb][row][32 * q + n];
            float4 b1 = xbuf[1][xb][row][32 * q + 16 + n];
            union { f16x8 v8; hf2 v2[4]; } u;
            u.v2[0] = __builtin_amdgcn_cvt_pkrtz(b0.x, b0.y);
            u.v2[1] = __builtin_amdgcn_cvt_pkrtz(b0.z, b0.w);
            u.v2[2] = __builtin_amdgcn_cvt_pkrtz(b1.x, b1.y);
            u.v2[3] = __builtin_amdgcn_cvt_pkrtz(b1.z, b1.w);
            axB = u.v8;
        }

        // ---- interleaved MFMA chains (A and B independent) ----
        f32x4 arA = __builtin_amdgcn_mfma_f32_16x16x32_f16(wi[0], axA, c_r, 0, 0, 0);
        f32x4 azA = __builtin_amdgcn_mfma_f32_16x16x32_f16(wi[1], axA, c_z, 0, 0, 0);
        f32x4 xnA = __builtin_amdgcn_mfma_f32_16x16x32_f16(wi[2], axA, c_xn, 0, 0, 0);
        f32x4 arB = c_r, azB = c_z, xnB = c_xn, hnB = c_hn;
        if (bAlive) {
            arB = __builtin_amdgcn_mfma_f32_16x16x32_f16(wi[0], axB, c_r, 0, 0, 0);
            azB = __builtin_amdgcn_mfma_f32_16x16x32_f16(wi[1], axB, c_z, 0, 0, 0);
            xnB = __builtin_amdgcn_mfma_f32_16x16x32_f16(wi[2], axB, c_xn, 0, 0, 0);
        }
        arA = __builtin_amdgcn_mfma_f32_16x16x32_f16(wh[0][0], bhA0, arA, 0, 0, 0);
        arA = __builtin_amdgcn_mfma_f32_16x16x32_f16(wh[0][1], bhA1, arA, 0, 0, 0);
        azA = __builtin_amdgcn_mfma_f32_16x16x32_f16(wh[1][0], bhA0, azA, 0, 0, 0);
        azA = __builtin_amdgcn_mfma_f32_16x16x32_f16(wh[1][1], bhA1, azA, 0, 0, 0);
        f32x4 hnA = __builtin_amdgcn_mfma_f32_16x16x32_f16(wh[2][0], bhA0, c_hn, 0, 0, 0);
        hnA = __builtin_amdgcn_mfma_f32_16x16x32_f16(wh[2][1], bhA1, hnA, 0, 0, 0);
        if (bAlive) {
            arB = __builtin_amdgcn_mfma_f32_16x16x32_f16(wh[0][0], bhB0, arB, 0, 0, 0);
            arB = __builtin_amdgcn_mfma_f32_16x16x32_f16(wh[0][1], bhB1, arB, 0, 0, 0);
            azB = __builtin_amdgcn_mfma_f32_16x16x32_f16(wh[1][0], bhB0, azB, 0, 0, 0);
            azB = __builtin_amdgcn_mfma_f32_16x16x32_f16(wh[1][1], bhB1, azB, 0, 0, 0);
            hnB = __builtin_amdgcn_mfma_f32_16x16x32_f16(wh[2][0], bhB0, c_hn, 0, 0, 0);
            hnB = __builtin_amdgcn_mfma_f32_16x16x32_f16(wh[2][1], bhB1, hnB, 0, 0, 0);
        }

        // ---- gates (A and B independent; compiler interleaves) ----
        {
            const bool live = (t < mylenA);
            #pragma unroll
            for (int r = 0; r < 4; ++r) {
                float rg    = __builtin_amdgcn_rcpf(1.f + __builtin_amdgcn_exp2f(arA[r]));
                float zg    = __builtin_amdgcn_rcpf(1.f + __builtin_amdgcn_exp2f(azA[r]));
                float inner = fmaf(rg, hnA[r], xnA[r]);
                float nn    = fmaf(-2.f, __builtin_amdgcn_rcpf(1.f + __builtin_amdgcn_exp2f(inner)), 1.f);
                float hnew  = fmaf(zg, holdA[r] - nn, nn);
                holdA[r] = live ? hnew : holdA[r];
            }
            union { f16x4 v4; hf2 v2[2]; } hu;
            hu.v2[0] = __builtin_amdgcn_cvt_pkrtz(holdA[0], holdA[1]);
            hu.v2[1] = __builtin_amdgcn_cvt_pkrtz(holdA[2], holdA[3]);
            *(f16x4*)&hbuf[0][cur ^ 1][n * 72 + colbase] = hu.v4;
        }
        if (bAlive) {
            const bool live = (t < mylenB);
            #pragma unroll
            for (int r = 0; r < 4; ++r) {
                float rg    = __builtin_amdgcn_rcpf(1.f + __builtin_amdgcn_exp2f(arB[r]));
                float zg    = __builtin_amdgcn_rcpf(1.f + __builtin_amdgcn_exp2f(azB[r]));
                float inner = fmaf(rg, hnB[r], xnB[r]);
                float nn    = fmaf(-2.f, __builtin_amdgcn_rcpf(1.f + __builtin_amdgcn_exp2f(inner)), 1.f);
                float hnew  = fmaf(zg, holdB[r] - nn, nn);
                holdB[r] = live ? hnew : holdB[r];
            }
            union { f16x4 v4; hf2 v2[2]; } hu;
            hu.v2[0] = __builtin_amdgcn_cvt_pkrtz(holdB[0], holdB[1]);
            hu.v2[1] = __builtin_amdgcn_cvt_pkrtz(holdB[2], holdB[3]);
            *(f16x4*)&hbuf[1][cur ^ 1][n * 72 + colbase] = hu.v4;
        }
        __syncthreads();
    }

    // ---- epilogue: both streams ----
    float partA = holdA[0] * wsc[0] + holdA[1] * wsc[1] +
                  holdA[2] * wsc[2] + holdA[3] * wsc[3];
    partA += __shfl_xor(partA, 16);
    partA += __shfl_xor(partA, 32);
    if (l < 16) red[0][w * 16 + n] = partA;
    float partB = holdB[0] * wsc[0] + holdB[1] * wsc[1] +
                  holdB[2] * wsc[2] + holdB[3] * wsc[3];
    partB += __shfl_xor(partB, 16);
    partB += __shfl_xor(partB, 32);
    if (l < 16) red[1][w * 16 + n] = partB;
    __syncthreads();

    // 16 threads per pair; two passes (A then B): softplus(pair MLP) * p_seq
    #pragma unroll
    for (int gs = 0; gs < 2; ++gs) {
        const int pbX = gs ? pbB : pbA;
        const int pp = tid >> 4;
        const int u  = tid & 15;
        const int pidx = perm[pbX + pp];
        const int ii = pidx >> 7;
        const int jj = pidx & 127;
        float acc = 0.f;
        #pragma unroll
        for (int cc = u; cc < PH; cc += 16)
            acc += Wp2[cc] * fmaxf(PA[ii * PH + cc] + PBt[cc * 128 + jj], 0.f);
        acc += __shfl_xor(acc, 1);
        acc += __shfl_xor(acc, 2);
        acc += __shfl_xor(acc, 4);
        acc += __shfl_xor(acc, 8);
        if (u == 0) {
            float z  = acc + bp2[0];
            float sp = fmaxf(z, 0.f) + log1pf(__expf(-fabsf(z)));
            float s  = red[gs][pp] + red[gs][16 + pp] + red[gs][32 + pp] + red[gs][48 + pp];
            float pv = fast_sigmoid(s + bs[0]);
            atomicAdd(d_out, sp * pv);
        }
    }
}

extern "C" void kernel_launch(void* const* d_in, const int* in_sizes, int n_in,
                              void* d_out, int out_size, void* d_ws, size_t ws_size,
                              hipStream_t stream)
{
    const float* O_feats = (const float*)d_in[0];
    const float* D_feats = (const float*)d_in[1];
    const float* seqs    = (const float*)d_in[2];
    const int*   lengths = (const int*)d_in[3];
    const float* WO1 = (const float*)d_in[4];  const float* bO1 = (const float*)d_in[5];
    const float* WO2 = (const float*)d_in[6];  const float* bO2 = (const float*)d_in[7];
    const float* WO3 = (const float*)d_in[8];  const float* bO3 = (const float*)d_in[9];
    const float* WD1 = (const float*)d_in[10]; const float* bD1 = (const float*)d_in[11];
    const float* WD2 = (const float*)d_in[12]; const float* bD2 = (const float*)d_in[13];
    const float* WD3 = (const float*)d_in[14]; const float* bD3 = (const float*)d_in[15];
    const float* Wp1 = (const float*)d_in[16]; const float* bp1 = (const float*)d_in[17];
    const float* Wp2 = (const float*)d_in[18]; const float* bp2 = (const float*)d_in[19];
    const float* W_ih = (const float*)d_in[20]; const float* b_ih = (const float*)d_in[21];
    const float* W_hh = (const float*)d_in[22]; const float* b_hh = (const float*)d_in[23];
    const float* Ws   = (const float*)d_in[24]; const float* bs   = (const float*)d_in[25];

    float* out    = (float*)d_out;
    float* PA     = (float*)d_ws;              // 16384 f
    float* PBt    = PA + 128 * 128;            // 16384 f (transposed, bp1 folded)
    int*   perm   = (int*)(PBt + 128 * 128);   // 16384 i

    k_pre<<<257, 256, 0, stream>>>(O_feats, D_feats,
                                   WO1, bO1, WO2, bO2, WO3, bO3,
                                   WD1, bD1, WD2, bD2, WD3, bD3,
                                   Wp1, bp1, lengths, PA, PBt, perm, out);
    k_gru<<<512, 256, 0, stream>>>(seqs, lengths, perm, W_ih, b_ih,
                                   W_hh, b_hh, Ws, bs, PA, PBt, Wp2, bp2, out);
}

// Round 10
// 345.453 us; speedup vs baseline: 1.0939x; 1.0939x over previous
//
#include <hip/hip_runtime.h>
#include <hip/hip_bf16.h>

#define O_N 128
#define D_N 128
#define F_LS 64
#define T_MAX 128
#define FE_N 16
#define H_GRU 64
#define NH 128
#define NO 64
#define PH 128
#define NGRP 1024

typedef _Float16 f16;
typedef __fp16 hf2 __attribute__((ext_vector_type(2)));
typedef f16 f16x4 __attribute__((ext_vector_type(4)));
typedef f16 f16x8 __attribute__((ext_vector_type(8)));
typedef float f32x4 __attribute__((ext_vector_type(4)));

__device__ __forceinline__ float fast_sigmoid(float x) {
    return __builtin_amdgcn_rcpf(1.f + __expf(-x));
}

// ---- fused: encoders (blocks 0..255) + counting sort (block 256) ----------
__global__ __launch_bounds__(256) void k_pre(
    const float* __restrict__ O_feats, const float* __restrict__ D_feats,
    const float* __restrict__ WO1, const float* __restrict__ bO1,
    const float* __restrict__ WO2, const float* __restrict__ bO2,
    const float* __restrict__ WO3, const float* __restrict__ bO3,
    const float* __restrict__ WD1, const float* __restrict__ bD1,
    const float* __restrict__ WD2, const float* __restrict__ bD2,
    const float* __restrict__ WD3, const float* __restrict__ bD3,
    const float* __restrict__ Wp1, const float* __restrict__ bp1,
    const int* __restrict__ lengths,
    float* __restrict__ PA, float* __restrict__ PBt,
    int* __restrict__ perm, float* __restrict__ d_out)
{
    const int t = threadIdx.x;
    if (blockIdx.x == 256) {
        __shared__ int cnt[130];
        __shared__ int suf[130];
        if (t < 130) cnt[t] = 0;
        __syncthreads();
        for (int i = t; i < 16384; i += 256) atomicAdd(&cnt[lengths[i]], 1);
        __syncthreads();
        if (t < 130) suf[t] = cnt[t];
        __syncthreads();
        for (int d = 1; d < 130; d <<= 1) {
            int v = 0;
            if (t < 130) { v = suf[t]; if (t + d < 130) v += suf[t + d]; }
            __syncthreads();
            if (t < 130) suf[t] = v;
            __syncthreads();
        }
        if (t < 129) cnt[t] = (t + 1 < 130) ? suf[t + 1] : 0;
        __syncthreads();
        for (int i = t; i < 16384; i += 256) {
            int pos = atomicAdd(&cnt[lengths[i]], 1);
            perm[pos] = i;
        }
        return;
    }

    __shared__ float h1[NH];
    __shared__ float h2[NH];
    __shared__ float ev[NO];
    const int b = blockIdx.x;
    const int enc = b >> 7;
    const int row = b & 127;
    if (b == 0 && t == 0) d_out[0] = 0.f;

    const float* x  = (enc ? D_feats : O_feats) + row * F_LS;
    const float* W1 = enc ? WD1 : WO1;  const float* b1 = enc ? bD1 : bO1;
    const float* W2 = enc ? WD2 : WO2;  const float* b2 = enc ? bD2 : bO2;
    const float* W3 = enc ? WD3 : WO3;  const float* b3 = enc ? bD3 : bO3;

    if (t < 128) {
        float a = b1[t];
        #pragma unroll 8
        for (int k = 0; k < F_LS; ++k) a += x[k] * W1[k * NH + t];
        h1[t] = fmaxf(a, 0.f);
    }
    __syncthreads();

    if (t < 128) {
        float a = b2[t];
        #pragma unroll 8
        for (int k = 0; k < NH; ++k) a += h1[k] * W2[k * NH + t];
        h2[t] = fmaxf(a, 0.f);
    }
    __syncthreads();

    if (t < NO) {
        float a = b3[t];
        #pragma unroll 8
        for (int k = 0; k < NH; ++k) a += h2[k] * W3[k * NO + t];
        ev[t] = a;
    }
    __syncthreads();

    if (t < 128) {
        const float* Wp = Wp1 + (enc ? NO * PH : 0);
        float a = 0.f;
        #pragma unroll 8
        for (int k = 0; k < NO; ++k) a += ev[k] * Wp[k * PH + t];
        if (enc) PBt[t * 128 + row] = a + bp1[t];   // transposed + bias folded
        else     PA[row * PH + t] = a;
    }
}

// ---- GRU: best-known structure (r5) + x software pipeline ------------------
// 1024 independent 4-wave blocks, identity map (empirically best across all
// remap attempts; co-residency topology unobservable). x staged through LDS
// double buffer in 8-step phases via global_load_lds (vmcnt drain amortized);
// xbuf transposed [row][chunk][pair]. NEW: ax for step t+1 is converted
// DURING step t (x is h-independent; its row is staged & drained >=1 barrier
// earlier) -> per-step chain starts at the h ds_read and the 3 x-MFMAs issue
// immediately at step start, hiding the h-read latency. Plain __syncthreads
// (counted waits regressed, r6). Wave w owns hidden cols [16w,16w+16);
// lane(q,n): pair n, cols 16w+4q+0..3. Pair-score MLP fused in epilogue.
__global__ __launch_bounds__(256, 4) void k_gru(
    const float* __restrict__ seqs, const int* __restrict__ lengths,
    const int* __restrict__ perm,
    const float* __restrict__ W_ih, const float* __restrict__ b_ih,
    const float* __restrict__ W_hh, const float* __restrict__ b_hh,
    const float* __restrict__ Ws, const float* __restrict__ bs,
    const float* __restrict__ PA, const float* __restrict__ PBt,
    const float* __restrict__ Wp2, const float* __restrict__ bp2,
    float* __restrict__ d_out)
{
    __shared__ __align__(16) f16 hbuf[2][16 * 72];      // [buf][pair][64+8 pad]
    __shared__ __align__(16) float4 xbuf[2][8][64];     // [buf][row][chunk*16+pair]
    __shared__ float red[64];
    const int tid = threadIdx.x;
    const int w  = tid >> 6;
    const int l  = tid & 63;
    const int q  = l >> 4;
    const int n  = l & 15;
    const int c  = w * 16 + n;          // W-frag column (m-row of A-tile)
    const int colbase = w * 16 + q * 4; // this lane's 4 hidden cols
    const int pb = blockIdx.x * 16;     // identity mapping
    const float S_RZ = -1.4426950408889634f;   // -log2(e)
    const float S_N  =  2.8853900817779268f;   // 2*log2(e)

    // W fragments (A-operand via m=lane&15):
    f16x8 wh[3][2], wi[3];
    #pragma unroll
    for (int gg = 0; gg < 3; ++gg) {
        const int gb = gg * 64;
        const float s = (gg < 2) ? S_RZ : S_N;
        #pragma unroll
        for (int ks = 0; ks < 2; ++ks)
            #pragma unroll
            for (int jj = 0; jj < 8; ++jj)
                wh[gg][ks][jj] = (f16)(W_hh[(ks * 32 + q * 8 + jj) * 192 + gb + c] * s);
        #pragma unroll
        for (int jj = 0; jj < 8; ++jj) {
            int k = q * 8 + jj;
            wi[gg][jj] = (k < FE_N) ? (f16)(W_ih[k * 192 + gb + c] * s) : (f16)0.f;
        }
    }
    // per-reg bias C-vectors and Ws for this lane's 4 cols
    f32x4 c_r, c_z, c_hn, c_xn;
    float wsc[4];
    #pragma unroll
    for (int r = 0; r < 4; ++r) {
        int col = colbase + r;
        c_r[r]  = S_RZ * (b_ih[col] + b_hh[col]);
        c_z[r]  = S_RZ * (b_ih[64 + col] + b_hh[64 + col]);
        c_hn[r] = S_N * b_hh[128 + col];
        c_xn[r] = S_N * b_ih[128 + col];
        wsc[r]  = Ws[col];
    }
    const int myp    = perm[pb + n];       // this lane's pair
    const int mylen  = lengths[myp];
    const int maxlen = lengths[perm[pb]];  // sorted desc -> group max

    // staging source: lane l covers slot l = (chunk l>>4, pair l&15)
    const float* xsrc = seqs + (size_t)perm[pb + (l & 15)] * (T_MAX * FE_N)
                       + (l >> 4) * 4;

    // zero h buffer 0 (2304 B = 144 x 16 B)
    if (tid < 144) { f16x8 z8 = {}; *(f16x8*)&hbuf[0][tid * 8] = z8; }

    // stage phase 0 (rows 0..7): wave w loads rows {w, w+4}
    #pragma unroll
    for (int rr = 0; rr < 2; ++rr) {
        const int r8 = w + rr * 4;
        __builtin_amdgcn_global_load_lds(
            (const __attribute__((address_space(1))) void*)(xsrc + (size_t)r8 * FE_N),
            (__attribute__((address_space(3))) void*)&xbuf[0][r8][0], 16, 0, 0);
    }
    float hold[4] = {0.f, 0.f, 0.f, 0.f};
    const f16x8 zero8 = {};
    __syncthreads();   // drains phase-0 staging + hbuf zero

    // prologue of x pipeline: ax for t=0
    f16x8 ax = zero8;
    if (q < 2) {
        float4 a0 = xbuf[0][0][32 * q + n];
        float4 a1 = xbuf[0][0][32 * q + 16 + n];
        union { f16x8 v8; hf2 v2[4]; } u;
        u.v2[0] = __builtin_amdgcn_cvt_pkrtz(a0.x, a0.y);
        u.v2[1] = __builtin_amdgcn_cvt_pkrtz(a0.z, a0.w);
        u.v2[2] = __builtin_amdgcn_cvt_pkrtz(a1.x, a1.y);
        u.v2[3] = __builtin_amdgcn_cvt_pkrtz(a1.z, a1.w);
        ax = u.v8;
    }

    #pragma unroll 1
    for (int t = 0; t < maxlen; ++t) {
        const int cur = t & 1;
        const int xb  = (t >> 3) & 1;
        const int row = t & 7;
        const f16* hb  = hbuf[cur];
        f16*       hbw = hbuf[cur ^ 1];

        // h reads (the only barrier-fresh dependency)
        f16x8 bh0 = *(const f16x8*)&hb[n * 72 + 8 * q];
        f16x8 bh1 = *(const f16x8*)&hb[n * 72 + 32 + 8 * q];

        // stage NEXT phase once per 8 steps (block-uniform condition)
        if (row == 0 && t + 8 < maxlen) {
            const int nb = xb ^ 1;
            #pragma unroll
            for (int rr = 0; rr < 2; ++rr) {
                const int rl = w + rr * 4;
                int rg = t + 8 + rl;
                rg = rg < T_MAX ? rg : T_MAX - 1;   // rows always allocated
                __builtin_amdgcn_global_load_lds(
                    (const __attribute__((address_space(1))) void*)(xsrc + (size_t)rg * FE_N),
                    (__attribute__((address_space(3))) void*)&xbuf[nb][rl][0], 16, 0, 0);
            }
        }

        // x-first MFMA chains: ax is already in registers (pipelined)
        f32x4 ar = __builtin_amdgcn_mfma_f32_16x16x32_f16(wi[0], ax, c_r, 0, 0, 0);
        f32x4 az = __builtin_amdgcn_mfma_f32_16x16x32_f16(wi[1], ax, c_z, 0, 0, 0);
        f32x4 xn = __builtin_amdgcn_mfma_f32_16x16x32_f16(wi[2], ax, c_xn, 0, 0, 0);
        ar = __builtin_amdgcn_mfma_f32_16x16x32_f16(wh[0][0], bh0, ar, 0, 0, 0);
        ar = __builtin_amdgcn_mfma_f32_16x16x32_f16(wh[0][1], bh1, ar, 0, 0, 0);
        az = __builtin_amdgcn_mfma_f32_16x16x32_f16(wh[1][0], bh0, az, 0, 0, 0);
        az = __builtin_amdgcn_mfma_f32_16x16x32_f16(wh[1][1], bh1, az, 0, 0, 0);
        f32x4 hn = __builtin_amdgcn_mfma_f32_16x16x32_f16(wh[2][0], bh0, c_hn, 0, 0, 0);
        hn = __builtin_amdgcn_mfma_f32_16x16x32_f16(wh[2][1], bh1, hn, 0, 0, 0);

        // prefetch+convert ax for step t+1 (its row is staged & drained
        // >= 1 barrier ago; the buffer written this step is the OTHER one)
        if (q < 2) {
            const int t1  = t + 1;
            const int xb1 = (t1 >> 3) & 1;
            const int r1  = t1 & 7;
            float4 a0 = xbuf[xb1][r1][32 * q + n];
            float4 a1 = xbuf[xb1][r1][32 * q + 16 + n];
            union { f16x8 v8; hf2 v2[4]; } u;
            u.v2[0] = __builtin_amdgcn_cvt_pkrtz(a0.x, a0.y);
            u.v2[1] = __builtin_amdgcn_cvt_pkrtz(a0.z, a0.w);
            u.v2[2] = __builtin_amdgcn_cvt_pkrtz(a1.x, a1.y);
            u.v2[3] = __builtin_amdgcn_cvt_pkrtz(a1.z, a1.w);
            ax = u.v8;
        }

        const bool live = (t < mylen);
        #pragma unroll
        for (int r = 0; r < 4; ++r) {
            float rg    = __builtin_amdgcn_rcpf(1.f + __builtin_amdgcn_exp2f(ar[r]));
            float zg    = __builtin_amdgcn_rcpf(1.f + __builtin_amdgcn_exp2f(az[r]));
            float inner = fmaf(rg, hn[r], xn[r]);
            float nn    = fmaf(-2.f, __builtin_amdgcn_rcpf(1.f + __builtin_amdgcn_exp2f(inner)), 1.f);
            float hnew  = fmaf(zg, hold[r] - nn, nn);
            hold[r] = live ? hnew : hold[r];
        }
        union { f16x4 v4; hf2 v2[2]; } hu;
        hu.v2[0] = __builtin_amdgcn_cvt_pkrtz(hold[0], hold[1]);
        hu.v2[1] = __builtin_amdgcn_cvt_pkrtz(hold[2], hold[3]);
        *(f16x4*)&hbw[n * 72 + colbase] = hu.v4;
        __syncthreads();
    }

    // ---- epilogue: p_seq = sigmoid(h @ Ws + bs); fused pair-score MLP ----
    float part = hold[0] * wsc[0] + hold[1] * wsc[1] +
                 hold[2] * wsc[2] + hold[3] * wsc[3];
    part += __shfl_xor(part, 16);
    part += __shfl_xor(part, 32);          // sum over q: wave-w partial, pair n
    if (l < 16) red[w * 16 + n] = part;
    __syncthreads();

    // 16 threads per pair: s_pair = softplus(Wp2 . relu(PA_i + PBt_j))
    const int pp = tid >> 4;               // pair 0..15
    const int u  = tid & 15;
    const int pidx = perm[pb + pp];
    const int ii = pidx >> 7;
    const int jj = pidx & 127;
    float acc = 0.f;
    #pragma unroll
    for (int cc = u; cc < PH; cc += 16)
        acc += Wp2[cc] * fmaxf(PA[ii * PH + cc] + PBt[cc * 128 + jj], 0.f);
    acc += __shfl_xor(acc, 1);
    acc += __shfl_xor(acc, 2);
    acc += __shfl_xor(acc, 4);
    acc += __shfl_xor(acc, 8);
    if (u == 0) {
        float z  = acc + bp2[0];
        float sp = fmaxf(z, 0.f) + log1pf(__expf(-fabsf(z)));
        float s  = red[pp] + red[16 + pp] + red[32 + pp] + red[48 + pp];
        float pv = fast_sigmoid(s + bs[0]);
        atomicAdd(d_out, sp * pv);
    }
}

extern "C" void kernel_launch(void* const* d_in, const int* in_sizes, int n_in,
                              void* d_out, int out_size, void* d_ws, size_t ws_size,
                              hipStream_t stream)
{
    const float* O_feats = (const float*)d_in[0];
    const float* D_feats = (const float*)d_in[1];
    const float* seqs    = (const float*)d_in[2];
    const int*   lengths = (const int*)d_in[3];
    const float* WO1 = (const float*)d_in[4];  const float* bO1 = (const float*)d_in[5];
    const float* WO2 = (const float*)d_in[6];  const float* bO2 = (const float*)d_in[7];
    const float* WO3 = (const float*)d_in[8];  const float* bO3 = (const float*)d_in[9];
    const float* WD1 = (const float*)d_in[10]; const float* bD1 = (const float*)d_in[11];
    const float* WD2 = (const float*)d_in[12]; const float* bD2 = (const float*)d_in[13];
    const float* WD3 = (const float*)d_in[14]; const float* bD3 = (const float*)d_in[15];
    const float* Wp1 = (const float*)d_in[16]; const float* bp1 = (const float*)d_in[17];
    const float* Wp2 = (const float*)d_in[18]; const float* bp2 = (const float*)d_in[19];
    const float* W_ih = (const float*)d_in[20]; const float* b_ih = (const float*)d_in[21];
    const float* W_hh = (const float*)d_in[22]; const float* b_hh = (const float*)d_in[23];
    const float* Ws   = (const float*)d_in[24]; const float* bs   = (const float*)d_in[25];

    float* out    = (float*)d_out;
    float* PA     = (float*)d_ws;              // 16384 f
    float* PBt    = PA + 128 * 128;            // 16384 f (transposed, bp1 folded)
    int*   perm   = (int*)(PBt + 128 * 128);   // 16384 i

    k_pre<<<257, 256, 0, stream>>>(O_feats, D_feats,
                                   WO1, bO1, WO2, bO2, WO3, bO3,
                                   WD1, bD1, WD2, bD2, WD3, bD3,
                                   Wp1, bp1, lengths, PA, PBt, perm, out);
    k_gru<<<1024, 256, 0, stream>>>(seqs, lengths, perm, W_ih, b_ih,
                                    W_hh, b_hh, Ws, bs, PA, PBt, Wp2, bp2, out);
}

// Round 11
// 332.794 us; speedup vs baseline: 1.1355x; 1.0380x over previous
//
#include <hip/hip_runtime.h>
#include <hip/hip_bf16.h>

#define O_N 128
#define D_N 128
#define F_LS 64
#define T_MAX 128
#define FE_N 16
#define H_GRU 64
#define NH 128
#define NO 64
#define PH 128

typedef _Float16 f16;
typedef __fp16 hf2 __attribute__((ext_vector_type(2)));
typedef f16 f16x4 __attribute__((ext_vector_type(4)));
typedef f16 f16x8 __attribute__((ext_vector_type(8)));
typedef float f32x4 __attribute__((ext_vector_type(4)));

__device__ __forceinline__ float fast_sigmoid(float x) {
    return __builtin_amdgcn_rcpf(1.f + __expf(-x));
}

// -------- encoders + PA / transposed-PB (bp1 folded) ; also zeroes d_out ----
__global__ __launch_bounds__(128) void k_enc(
    const float* __restrict__ O_feats, const float* __restrict__ D_feats,
    const float* __restrict__ WO1, const float* __restrict__ bO1,
    const float* __restrict__ WO2, const float* __restrict__ bO2,
    const float* __restrict__ WO3, const float* __restrict__ bO3,
    const float* __restrict__ WD1, const float* __restrict__ bD1,
    const float* __restrict__ WD2, const float* __restrict__ bD2,
    const float* __restrict__ WD3, const float* __restrict__ bD3,
    const float* __restrict__ Wp1, const float* __restrict__ bp1,
    float* __restrict__ PA, float* __restrict__ PBt, float* __restrict__ d_out)
{
    __shared__ float h1[NH];
    __shared__ float h2[NH];
    __shared__ float ev[NO];
    const int b = blockIdx.x;
    const int enc = b >> 7;
    const int row = b & 127;
    const int t = threadIdx.x;
    if (b == 0 && t == 0) d_out[0] = 0.f;

    const float* x  = (enc ? D_feats : O_feats) + row * F_LS;
    const float* W1 = enc ? WD1 : WO1;  const float* b1 = enc ? bD1 : bO1;
    const float* W2 = enc ? WD2 : WO2;  const float* b2 = enc ? bD2 : bO2;
    const float* W3 = enc ? WD3 : WO3;  const float* b3 = enc ? bD3 : bO3;

    float a = b1[t];
    #pragma unroll 8
    for (int k = 0; k < F_LS; ++k) a += x[k] * W1[k * NH + t];
    h1[t] = fmaxf(a, 0.f);
    __syncthreads();

    a = b2[t];
    #pragma unroll 8
    for (int k = 0; k < NH; ++k) a += h1[k] * W2[k * NH + t];
    h2[t] = fmaxf(a, 0.f);
    __syncthreads();

    if (t < NO) {
        a = b3[t];
        #pragma unroll 8
        for (int k = 0; k < NH; ++k) a += h2[k] * W3[k * NO + t];
        ev[t] = a;
    }
    __syncthreads();

    const float* Wp = Wp1 + (enc ? NO * PH : 0);
    a = 0.f;
    #pragma unroll 8
    for (int k = 0; k < NO; ++k) a += ev[k] * Wp[k * PH + t];
    if (enc) PBt[t * 128 + row] = a + bp1[t];   // transposed + bias folded
    else     PA[row * PH + t] = a;
}

// ---------------- pair scores (coalesced PBt stream) ----------------
__global__ __launch_bounds__(128) void k_pair(
    const float* __restrict__ PA, const float* __restrict__ PBt,
    const float* __restrict__ Wp2, const float* __restrict__ bp2,
    float* __restrict__ s_pair)
{
    const int i = blockIdx.x;
    const int j = threadIdx.x;
    __shared__ float pa[PH];
    __shared__ float w2s[PH];
    pa[j]  = PA[i * PH + j];
    w2s[j] = Wp2[j];
    __syncthreads();
    float acc = 0.f;
    #pragma unroll 8
    for (int c = 0; c < PH; ++c)
        acc += w2s[c] * fmaxf(pa[c] + PBt[c * 128 + j], 0.f);
    float z = acc + bp2[0];
    float sp = fmaxf(z, 0.f) + log1pf(__expf(-fabsf(z)));
    s_pair[i * 128 + j] = sp;
}

// ------- counting sort by length, DESCENDING, one block, LDS atomics -------
__global__ __launch_bounds__(1024) void k_sort(
    const int* __restrict__ lengths, int* __restrict__ perm)
{
    __shared__ int cnt[130];
    __shared__ int suf[130];
    const int t = threadIdx.x;
    if (t < 130) cnt[t] = 0;
    __syncthreads();
    for (int i = t; i < 16384; i += 1024) atomicAdd(&cnt[lengths[i]], 1);
    __syncthreads();
    if (t < 130) suf[t] = cnt[t];
    __syncthreads();
    for (int d = 1; d < 130; d <<= 1) {
        int v = 0;
        if (t < 130) { v = suf[t]; if (t + d < 130) v += suf[t + d]; }
        __syncthreads();
        if (t < 130) suf[t] = v;
        __syncthreads();
    }
    if (t < 129) cnt[t] = (t + 1 < 130) ? suf[t + 1] : 0;
    __syncthreads();
    for (int i = t; i < 16384; i += 1024) {
        int pos = atomicAdd(&cnt[lengths[i]], 1);
        perm[pos] = i;
    }
}

// ---- GRU: r5-exact structure + counted waits / staging stagger ------------
// 1024 independent 4-wave blocks, identity map (best known). x staged through
// LDS double buffer in 8-step phases via global_load_lds; xbuf r5 layout
// [row][pair][16]. ONLY delta vs the 92.6us r5 artifact: stage issued at
// row==srow (srow=blk&3, de-convoys blocks) and drained by an explicit
// vmcnt(0) at row 7 only -- 4-7 steps of HBM latency hiding instead of
// same-step drain; every step ends lgkmcnt(0) + raw s_barrier.
// Wave w owns hidden cols [16w,16w+16); lane(q,n): pair n, cols 16w+4q+0..3.
__global__ __launch_bounds__(256, 4) void k_gru(
    const float* __restrict__ seqs, const int* __restrict__ lengths,
    const int* __restrict__ perm,
    const float* __restrict__ W_ih, const float* __restrict__ b_ih,
    const float* __restrict__ W_hh, const float* __restrict__ b_hh,
    const float* __restrict__ Ws, const float* __restrict__ bs,
    const float* __restrict__ s_pair, float* __restrict__ d_out)
{
    __shared__ __align__(16) f16 hbuf[2][16 * 72];      // [buf][pair][64+8 pad]
    __shared__ __align__(16) float xbuf[2][8][16][16];  // [buf][row][pair][16 f32]
    __shared__ float red[64];
    const int tid = threadIdx.x;
    const int w  = tid >> 6;
    const int l  = tid & 63;
    const int q  = l >> 4;
    const int n  = l & 15;
    const int c  = w * 16 + n;          // W-frag column (m-row of A-tile)
    const int colbase = w * 16 + q * 4; // this lane's 4 hidden cols
    const int pb = blockIdx.x * 16;     // identity mapping
    const int srow = blockIdx.x & 3;    // staging-phase stagger
    const float S_RZ = -1.4426950408889634f;   // -log2(e)
    const float S_N  =  2.8853900817779268f;   // 2*log2(e)

    // W fragments (A-operand via m=lane&15):
    f16x8 wh[3][2], wi[3];
    #pragma unroll
    for (int gg = 0; gg < 3; ++gg) {
        const int gb = gg * 64;
        const float s = (gg < 2) ? S_RZ : S_N;
        #pragma unroll
        for (int ks = 0; ks < 2; ++ks)
            #pragma unroll
            for (int jj = 0; jj < 8; ++jj)
                wh[gg][ks][jj] = (f16)(W_hh[(ks * 32 + q * 8 + jj) * 192 + gb + c] * s);
        #pragma unroll
        for (int jj = 0; jj < 8; ++jj) {
            int k = q * 8 + jj;
            wi[gg][jj] = (k < FE_N) ? (f16)(W_ih[k * 192 + gb + c] * s) : (f16)0.f;
        }
    }
    // per-reg bias C-vectors and Ws for this lane's 4 cols
    f32x4 c_r, c_z, c_hn, c_xn;
    float wsc[4];
    #pragma unroll
    for (int r = 0; r < 4; ++r) {
        int col = colbase + r;
        c_r[r]  = S_RZ * (b_ih[col] + b_hh[col]);
        c_z[r]  = S_RZ * (b_ih[64 + col] + b_hh[64 + col]);
        c_hn[r] = S_N * b_hh[128 + col];
        c_xn[r] = S_N * b_ih[128 + col];
        wsc[r]  = Ws[col];
    }
    const int myp   = perm[pb + n];      // this lane's pair
    const int mylen = lengths[myp];
    int ml = mylen;
    ml = max(ml, __shfl_xor(ml, 1));
    ml = max(ml, __shfl_xor(ml, 2));
    ml = max(ml, __shfl_xor(ml, 4));
    ml = max(ml, __shfl_xor(ml, 8));
    const int maxlen = __builtin_amdgcn_readfirstlane(ml);

    // staging source: lane covers (pair l>>2, floats [4*(l&3), 4*(l&3)+4))
    const float* xsrc = seqs + (size_t)perm[pb + (l >> 2)] * (T_MAX * FE_N)
                       + (l & 3) * 4;

    // zero h buffer 0 (2304 B = 144 x 16 B)
    if (tid < 144) { f16x8 z8 = {}; *(f16x8*)&hbuf[0][tid * 8] = z8; }

    // stage phase 0 (rows 0..7): wave w loads rows {w, w+4}
    #pragma unroll
    for (int rr = 0; rr < 2; ++rr) {
        const int r8 = w + rr * 4;
        __builtin_amdgcn_global_load_lds(
            (const __attribute__((address_space(1))) void*)(xsrc + (size_t)r8 * FE_N),
            (__attribute__((address_space(3))) void*)&xbuf[0][r8][0][0], 16, 0, 0);
    }
    float hold[4] = {0.f, 0.f, 0.f, 0.f};
    const f16x8 zero8 = {};
    __syncthreads();   // full drain: phase-0 staging + hbuf zero

    #pragma unroll 1
    for (int t = 0; t < maxlen; ++t) {
        const int cur = t & 1;
        const int xb  = (t >> 3) & 1;
        const int row = t & 7;
        const f16* hb  = hbuf[cur];
        f16*       hbw = hbuf[cur ^ 1];
        // issue LDS reads first (latency), staging + x-convert fill the gap
        f16x8 bh0 = *(const f16x8*)&hb[n * 72 + 8 * q];
        f16x8 bh1 = *(const f16x8*)&hb[n * 72 + 32 + 8 * q];

        // stage NEXT phase once per 8 steps at per-block stagger row
        if (row == srow && (t - srow) + 8 < maxlen) {
            const int nb = xb ^ 1;
            const int tp8 = (t - srow) + 8;
            #pragma unroll
            for (int rr = 0; rr < 2; ++rr) {
                const int rl = w + rr * 4;
                int rg = tp8 + rl;
                rg = rg < T_MAX ? rg : T_MAX - 1;   // rows always allocated
                __builtin_amdgcn_global_load_lds(
                    (const __attribute__((address_space(1))) void*)(xsrc + (size_t)rg * FE_N),
                    (__attribute__((address_space(3))) void*)&xbuf[nb][rl][0][0], 16, 0, 0);
            }
        }

        f16x8 ax = zero8;                 // q>=2 lanes contribute zeros (K pad)
        if (q < 2) {
            const float* xr = &xbuf[xb][row][n][q * 8];
            float4 a0 = *(const float4*)xr;
            float4 a1 = *(const float4*)(xr + 4);
            union { f16x8 v8; hf2 v2[4]; } u;
            u.v2[0] = __builtin_amdgcn_cvt_pkrtz(a0.x, a0.y);
            u.v2[1] = __builtin_amdgcn_cvt_pkrtz(a0.z, a0.w);
            u.v2[2] = __builtin_amdgcn_cvt_pkrtz(a1.x, a1.y);
            u.v2[3] = __builtin_amdgcn_cvt_pkrtz(a1.z, a1.w);
            ax = u.v8;
        }

        // x-first MFMA chains (no LDS dep on first op of r/z/xn)
        f32x4 ar = __builtin_amdgcn_mfma_f32_16x16x32_f16(wi[0], ax, c_r, 0, 0, 0);
        f32x4 az = __builtin_amdgcn_mfma_f32_16x16x32_f16(wi[1], ax, c_z, 0, 0, 0);
        f32x4 xn = __builtin_amdgcn_mfma_f32_16x16x32_f16(wi[2], ax, c_xn, 0, 0, 0);
        ar = __builtin_amdgcn_mfma_f32_16x16x32_f16(wh[0][0], bh0, ar, 0, 0, 0);
        ar = __builtin_amdgcn_mfma_f32_16x16x32_f16(wh[0][1], bh1, ar, 0, 0, 0);
        az = __builtin_amdgcn_mfma_f32_16x16x32_f16(wh[1][0], bh0, az, 0, 0, 0);
        az = __builtin_amdgcn_mfma_f32_16x16x32_f16(wh[1][1], bh1, az, 0, 0, 0);
        f32x4 hn = __builtin_amdgcn_mfma_f32_16x16x32_f16(wh[2][0], bh0, c_hn, 0, 0, 0);
        hn = __builtin_amdgcn_mfma_f32_16x16x32_f16(wh[2][1], bh1, hn, 0, 0, 0);

        const bool live = (t < mylen);
        #pragma unroll
        for (int r = 0; r < 4; ++r) {
            float rg    = __builtin_amdgcn_rcpf(1.f + __builtin_amdgcn_exp2f(ar[r]));
            float zg    = __builtin_amdgcn_rcpf(1.f + __builtin_amdgcn_exp2f(az[r]));
            float inner = fmaf(rg, hn[r], xn[r]);
            float nn    = fmaf(-2.f, __builtin_amdgcn_rcpf(1.f + __builtin_amdgcn_exp2f(inner)), 1.f);
            float hnew  = fmaf(zg, hold[r] - nn, nn);
            hold[r] = live ? hnew : hold[r];
        }
        union { f16x4 v4; hf2 v2[2]; } hu;
        hu.v2[0] = __builtin_amdgcn_cvt_pkrtz(hold[0], hold[1]);
        hu.v2[1] = __builtin_amdgcn_cvt_pkrtz(hold[2], hold[3]);
        *(f16x4*)&hbw[n * 72 + colbase] = hu.v4;

        // counted-wait barrier: drain vmem only at row 7 (staging has 4-7
        // steps of lead); every step drains LDS (h write) then s_barrier.
        if (row == 7) asm volatile("s_waitcnt vmcnt(0)" ::: "memory");
        asm volatile("s_waitcnt lgkmcnt(0)" ::: "memory");
        __builtin_amdgcn_s_barrier();
    }

    // epilogue: p_seq = sigmoid(h @ Ws + bs); contrib = s_pair * p_seq
    float part = hold[0] * wsc[0] + hold[1] * wsc[1] +
                 hold[2] * wsc[2] + hold[3] * wsc[3];
    part += __shfl_xor(part, 16);
    part += __shfl_xor(part, 32);          // sum over q: wave-w partial, pair n
    if (l < 16) red[w * 16 + n] = part;
    __syncthreads();
    if (tid < 16) {
        float s = red[tid] + red[16 + tid] + red[32 + tid] + red[48 + tid];
        float pv = fast_sigmoid(s + bs[0]);
        float contrib = s_pair[perm[pb + tid]] * pv;
        #pragma unroll
        for (int off = 1; off < 16; off <<= 1)
            contrib += __shfl_xor(contrib, off);
        if (tid == 0) atomicAdd(d_out, contrib);
    }
}

extern "C" void kernel_launch(void* const* d_in, const int* in_sizes, int n_in,
                              void* d_out, int out_size, void* d_ws, size_t ws_size,
                              hipStream_t stream)
{
    const float* O_feats = (const float*)d_in[0];
    const float* D_feats = (const float*)d_in[1];
    const float* seqs    = (const float*)d_in[2];
    const int*   lengths = (const int*)d_in[3];
    const float* WO1 = (const float*)d_in[4];  const float* bO1 = (const float*)d_in[5];
    const float* WO2 = (const float*)d_in[6];  const float* bO2 = (const float*)d_in[7];
    const float* WO3 = (const float*)d_in[8];  const float* bO3 = (const float*)d_in[9];
    const float* WD1 = (const float*)d_in[10]; const float* bD1 = (const float*)d_in[11];
    const float* WD2 = (const float*)d_in[12]; const float* bD2 = (const float*)d_in[13];
    const float* WD3 = (const float*)d_in[14]; const float* bD3 = (const float*)d_in[15];
    const float* Wp1 = (const float*)d_in[16]; const float* bp1 = (const float*)d_in[17];
    const float* Wp2 = (const float*)d_in[18]; const float* bp2 = (const float*)d_in[19];
    const float* W_ih = (const float*)d_in[20]; const float* b_ih = (const float*)d_in[21];
    const float* W_hh = (const float*)d_in[22]; const float* b_hh = (const float*)d_in[23];
    const float* Ws   = (const float*)d_in[24]; const float* bs   = (const float*)d_in[25];

    float* out    = (float*)d_out;
    float* PA     = (float*)d_ws;              // 16384 f
    float* PBt    = PA + 128 * 128;            // 16384 f (transposed, bp1 folded)
    float* s_pair = PBt + 128 * 128;           // 16384 f
    int*   perm   = (int*)(s_pair + 16384);    // 16384 i

    k_enc<<<256, 128, 0, stream>>>(O_feats, D_feats,
                                   WO1, bO1, WO2, bO2, WO3, bO3,
                                   WD1, bD1, WD2, bD2, WD3, bD3,
                                   Wp1, bp1, PA, PBt, out);
    k_pair<<<128, 128, 0, stream>>>(PA, PBt, Wp2, bp2, s_pair);
    k_sort<<<1, 1024, 0, stream>>>(lengths, perm);
    k_gru<<<1024, 256, 0, stream>>>(seqs, lengths, perm, W_ih, b_ih, W_hh, b_hh,
                                    Ws, bs, s_pair, out);
}